// Round 7
// baseline (542.338 us; speedup 1.0000x reference)
//
#include <hip/hip_runtime.h>

typedef unsigned short ushort_t;
typedef __attribute__((ext_vector_type(8))) short short8;
typedef __attribute__((ext_vector_type(4))) float f32x4;

#define B_ 2
#define HW_ 65536          // 256*256 per batch
#define MTOT_ 131072       // B*H*W rows
#define C_ 192
#define C3_ 576
#define HEADS_ 4
#define CH_ 48

// ---- workspace layout (bytes), total ~302.5 MB ----
#define OFF_QKV0  ((size_t)0)                       // bf16 131072*576*2 = 150,994,944
#define OFF_QKV1  ((size_t)150994944)               // bf16, same size
#define OFF_P     OFF_QKV0                          // gram partials (15.7 MB) alias qkv0: dead after dwconv
#define OFF_BT    ((size_t)301989888)               // w_qkv^T bf16 576*192*2 = 221,184
#define OFF_S     ((size_t)302211072)               // fp32 8*48*48 = 73,728 B
#define OFF_NQ    ((size_t)302284800)               // fp32 8*48 = 1,536 B
#define OFF_NK    ((size_t)302286336)               // fp32 8*48 = 1,536 B
#define OFF_ATTN  ((size_t)302287872)               // fp32 8*48*48 = 73,728 B
#define OFF_MT    ((size_t)302361600)               // bf16 2*192*192 = 147,456 B

__device__ __forceinline__ float b2f(ushort_t u) {
    unsigned v = ((unsigned)u) << 16;
    return __builtin_bit_cast(float, v);
}
__device__ __forceinline__ ushort_t f2b(float f) {
    unsigned u = __builtin_bit_cast(unsigned, f);
    u = (u + 0x7fffu + ((u >> 16) & 1u)) >> 16;   // RNE
    return (ushort_t)u;
}
__device__ __forceinline__ void storev(float* p, float v) { *p = v; }
__device__ __forceinline__ void storev(ushort_t* p, float v) { *p = f2b(v); }

// stage 48 contiguous A-elements (one row-quarter) into LDS as bf16.
// bf16 input: straight 6x uint4 copy.  fp32 input: 12x float4 + RNE convert
// (bit-identical to the old k_cvt_x pass).
__device__ __forceinline__ void stage48(const ushort_t* __restrict__ g, ushort_t* l) {
#pragma unroll
    for (int j = 0; j < 6; ++j)
        *(uint4*)(l + j * 8) = *(const uint4*)(g + j * 8);
}
__device__ __forceinline__ void stage48(const float* __restrict__ g, ushort_t* l) {
#pragma unroll
    for (int j = 0; j < 6; ++j) {
        float4 a = *(const float4*)(g + j * 8);
        float4 b = *(const float4*)(g + j * 8 + 4);
        ushort_t o[8];
        o[0] = f2b(a.x); o[1] = f2b(a.y); o[2] = f2b(a.z); o[3] = f2b(a.w);
        o[4] = f2b(b.x); o[5] = f2b(b.y); o[6] = f2b(b.z); o[7] = f2b(b.w);
        *(uint4*)(l + j * 8) = *(uint4*)o;
    }
}

// K0: transpose+convert w_qkv fp32 [192,576] -> bf16 [576,192]
__global__ void k0_transpose(const float* __restrict__ w, ushort_t* __restrict__ bt) {
    int idx = blockIdx.x * 256 + threadIdx.x;        // 576*192 = 110592 exactly
    int n = idx / 192, k = idx - n * 192;
    bt[idx] = f2b(w[k * 576 + n]);
}

// MFMA GEMM: C[M,N] = A[M,192] * BT[N,192]^T(bf16) + bias(fp32).  A fp32 (converted
// during staging) or bf16.  64x64 tile, 4 waves each 32x32 (2x2 of 16x16x32 mfma).
// SINGLE-SHOT K: the full 64x192 A and B tiles are staged at once (18 independent
// 16B loads/thread = deep MLP in one latency window), ONE barrier, then 24
// straight-line ds_read+MFMA per wave.  Round-6 profile showed the 3-iter
// 2-barrier K-loop was latency-bound: all pipes <25% (MfmaUtil 8, VALU 23,
// HBM 17%) at 145us.  LDS row stride 200 elems (100 words = 4 mod 32: rows
// spread over 8 banks, 2-way aliasing = free, same pattern as the old 72).
// 2x25.6KB LDS -> 3 blocks/CU.
// 1-D grid + bijective XCD swizzle (round-6: FETCH 395->50MB, keep it).
// Requires gridDim.x % 8 == 0 and (gridDim.x/8) % ntn == 0 (18432/6144 ok).
template <typename AT, typename OutT>
__global__ __launch_bounds__(256) void gemm_k192(
    const AT* __restrict__ A, int lda, int acol0,
    const ushort_t* __restrict__ BT, int bstride, int ntn,
    const float* __restrict__ bias,
    OutT* __restrict__ Cout, int ldc)
{
    const int per = gridDim.x >> 3;
    const int bid = blockIdx.x;
    const int lb  = (bid & 7) * per + (bid >> 3);
    const int mt  = lb / ntn;
    const int m0  = mt * 64;
    const int n0  = (lb - mt * ntn) * 64;
    const ushort_t* bt = BT + (bstride ? (size_t)(m0 >> 16) * (size_t)bstride : 0);

    __shared__ ushort_t As[64 * 200];
    __shared__ ushort_t Bs[64 * 200];

    const int t = threadIdx.x;
    const int wave = t >> 6, lane = t & 63;
    const int quad = lane >> 4, l15 = lane & 15;
    const int wm = (wave >> 1) * 32, wn = (wave & 1) * 32;
    const int r  = t & 63, cb = t >> 6;      // staging: row r, col-quarter cb (48 elems)

    // ---- single-shot staging of the full K=192 tiles ----
    stage48(A + (size_t)(m0 + r) * lda + acol0 + cb * 48, &As[r * 200 + cb * 48]);
    {
        const ushort_t* gb = bt + (size_t)(n0 + r) * 192 + cb * 48;
#pragma unroll
        for (int j = 0; j < 6; ++j)
            *(uint4*)&Bs[r * 200 + cb * 48 + j * 8] = *(const uint4*)(gb + j * 8);
    }
    __syncthreads();

    f32x4 acc[2][2] = {};
#pragma unroll
    for (int ks = 0; ks < 6; ks++) {
        short8 a0 = *(const short8*)&As[(wm + l15) * 200 + ks * 32 + quad * 8];
        short8 a1 = *(const short8*)&As[(wm + 16 + l15) * 200 + ks * 32 + quad * 8];
        short8 b0 = *(const short8*)&Bs[(wn + l15) * 200 + ks * 32 + quad * 8];
        short8 b1 = *(const short8*)&Bs[(wn + 16 + l15) * 200 + ks * 32 + quad * 8];
        acc[0][0] = __builtin_amdgcn_mfma_f32_16x16x32_bf16(a0, b0, acc[0][0], 0, 0, 0);
        acc[0][1] = __builtin_amdgcn_mfma_f32_16x16x32_bf16(a0, b1, acc[0][1], 0, 0, 0);
        acc[1][0] = __builtin_amdgcn_mfma_f32_16x16x32_bf16(a1, b0, acc[1][0], 0, 0, 0);
        acc[1][1] = __builtin_amdgcn_mfma_f32_16x16x32_bf16(a1, b1, acc[1][1], 0, 0, 0);
    }

#pragma unroll
    for (int sm = 0; sm < 2; sm++) {
#pragma unroll
        for (int sn = 0; sn < 2; sn++) {
            int col = n0 + wn + sn * 16 + l15;
            float bv = bias ? bias[col] : 0.f;
#pragma unroll
            for (int rr = 0; rr < 4; rr++) {
                int row = m0 + wm + sm * 16 + quad * 4 + rr;
                storev(&Cout[(size_t)row * ldc + col], acc[sm][sn][rr] + bv);
            }
        }
    }
}

// K2: 3x3 depthwise conv, SAME zero-pad, fp32 weights/bias, bf16 act in/out.
// Register-sliding, 4 channels/thread: each thread owns (b, x, c4) and a strip
// of 16 output rows.  Threads: 2*16*256*144 = 1,179,648 -> grid 4608 x 256.
#define R_STRIP 16

__global__ __launch_bounds__(256) void k2_dwconv(const ushort_t* __restrict__ qkv0,
        const float* __restrict__ wdw, const float* __restrict__ bdw,
        ushort_t* __restrict__ qkv1)
{
    const int tid = blockIdx.x * 256 + threadIdx.x;   // < 1,179,648
    const int c4 = tid % 144;
    const int t1 = tid / 144;                 // = (b*16 + s)*256 + x, < 8192
    const int x  = t1 & 255;
    const int t2 = t1 >> 8;
    const int s  = t2 & 15;
    const int b  = t2 >> 4;
    const int y0 = s * R_STRIP;
    const int cbase = c4 * 4;

    const bool xm = (x > 0), xp = (x < 255);
    const ushort_t* colbase = qkv0 + ((size_t)(b * HW_ + x) * C3_ + cbase);
    ushort_t*       ocol    = qkv1 + ((size_t)(b * HW_ + x) * C3_ + cbase);
    const size_t rstride = (size_t)256 * C3_;         // elems per image row

    // preload weights [ky][kx][4] and bias (coalesced float4 reads, L2-hot)
    float w[3][3][4], bw[4];
#pragma unroll
    for (int ky = 0; ky < 3; ++ky)
#pragma unroll
        for (int kx = 0; kx < 3; ++kx) {
            float4 wv = *(const float4*)(wdw + ((ky * 3 + kx) * C3_ + cbase));
            w[ky][kx][0] = wv.x; w[ky][kx][1] = wv.y; w[ky][kx][2] = wv.z; w[ky][kx][3] = wv.w;
        }
    {
        float4 bv = *(const float4*)(bdw + cbase);
        bw[0] = bv.x; bw[1] = bv.y; bw[2] = bv.z; bw[3] = bv.w;
    }

    const uint2 z2 = make_uint2(0, 0);
    auto loadrow = [&](int r, uint2& d0, uint2& d1, uint2& d2) {
        if ((unsigned)r <= 255u) {
            const ushort_t* p = colbase + (size_t)r * rstride;
            d1 = *(const uint2*)p;
            d0 = xm ? *(const uint2*)(p - C3_) : z2;
            d2 = xp ? *(const uint2*)(p + C3_) : z2;
        } else { d0 = z2; d1 = z2; d2 = z2; }
    };

    // acc role: output row o uses A[(o - y0 + 1) % 3]; at step RR (input row
    // r = y0-1+RR): prev-out(r-1) -> (RR+2)%3, cur-out(r) -> RR%3,
    // next-out(r+1) -> (RR+1)%3 — all compile-time after unroll.
    float A[3][4] = {};
    uint2 c0, c1, c2;
    loadrow(y0 - 1, c0, c1, c2);

#pragma unroll
    for (int RR = 0; RR < R_STRIP + 2; ++RR) {
        const int r = y0 - 1 + RR;
        uint2 n0 = z2, n1 = z2, n2 = z2;
        if (RR < R_STRIP + 1) loadrow(r + 1, n0, n1, n2);   // 1-step prefetch

        float rf[3][4];
        {
            const ushort_t* dd = (const ushort_t*)&c0;
#pragma unroll
            for (int j = 0; j < 4; ++j) rf[0][j] = b2f(dd[j]);
            dd = (const ushort_t*)&c1;
#pragma unroll
            for (int j = 0; j < 4; ++j) rf[1][j] = b2f(dd[j]);
            dd = (const ushort_t*)&c2;
#pragma unroll
            for (int j = 0; j < 4; ++j) rf[2][j] = b2f(dd[j]);
        }

        if (RR >= 1 && RR <= R_STRIP) {           // row r -> out r (ky=0 center)
#pragma unroll
            for (int kx = 0; kx < 3; ++kx)
#pragma unroll
                for (int j = 0; j < 4; ++j)
                    A[RR % 3][j] = fmaf(rf[kx][j], w[1][kx][j], A[RR % 3][j]);
        }
        if (RR <= R_STRIP - 1) {                  // row r -> out r+1 (ky=-1)
#pragma unroll
            for (int kx = 0; kx < 3; ++kx)
#pragma unroll
                for (int j = 0; j < 4; ++j)
                    A[(RR + 1) % 3][j] = fmaf(rf[kx][j], w[0][kx][j], A[(RR + 1) % 3][j]);
        }
        if (RR >= 2) {                            // row r -> out r-1 (ky=+1), emit r-1
#pragma unroll
            for (int kx = 0; kx < 3; ++kx)
#pragma unroll
                for (int j = 0; j < 4; ++j)
                    A[(RR + 2) % 3][j] = fmaf(rf[kx][j], w[2][kx][j], A[(RR + 2) % 3][j]);
            ushort_t ov[4];
#pragma unroll
            for (int j = 0; j < 4; ++j) {
                ov[j] = f2b(A[(RR + 2) % 3][j] + bw[j]);
                A[(RR + 2) % 3][j] = 0.f;
            }
            *(uint2*)(ocol + (size_t)(r - 1) * rstride) = *(uint2*)ov;
        }
        c0 = n0; c1 = n1; c2 = n2;
    }
}

// K3 (MFMA): per (b,head) 96x96 Gram of Z=[Q|K] over a 1024-row slice.
#define GR_LDSSTRIDE 136

__global__ __launch_bounds__(256) void k3_gram_mfma(const ushort_t* __restrict__ qkv1,
        float* __restrict__ P)
{
    const int bh = blockIdx.y;              // 0..7
    const int b = bh >> 2, h = bh & 3;
    const int slice = blockIdx.x;           // 0..63
    const int t = threadIdx.x;
    const int wave = t >> 6, lane = t & 63;
    const int quad = lane >> 4, l15 = lane & 15;

    __shared__ float red[7680];             // 30,720 B; low 26,112 B doubles as bf16 stage
    ushort_t* Z = (ushort_t*)red;

    f32x4 acc[15] = {};
    const ushort_t* basep = qkv1 + (size_t)(b * HW_) * C3_;
    const int row = t & 127;
    const int seghalf = t >> 7;             // 0: even segs, 1: odd segs

    for (int tile = 0; tile < 8; ++tile) {
        const int nbase = slice * 1024 + tile * 128;
        uint4 u[6];
#pragma unroll
        for (int k = 0; k < 6; ++k) {       // issue loads before barrier: overlap prev compute
            int seg = k * 2 + seghalf;      // 0..11; segs 0-5 = Q chans, 6-11 = K chans
            int cg = (seg < 6) ? (h * CH_ + seg * 8) : (C_ + h * CH_ + (seg - 6) * 8);
            u[k] = *(const uint4*)(basep + (size_t)(nbase + row) * C3_ + cg);
        }
        __syncthreads();                    // previous tile's compute done
#pragma unroll
        for (int k = 0; k < 6; ++k) {
            int seg = k * 2 + seghalf;
            int zc = seg * 8;               // z-channel base (Q:0-47, K:48-95)
            const ushort_t* dd = (const ushort_t*)&u[k];
#pragma unroll
            for (int j = 0; j < 8; ++j)
                Z[(zc + j) * GR_LDSSTRIDE + row] = dd[j];
        }
        __syncthreads();
        const int n0 = wave * 32 + quad * 8;
        short8 F[6];
#pragma unroll
        for (int c = 0; c < 6; ++c)
            F[c] = *(const short8*)&Z[(c * 16 + l15) * GR_LDSSTRIDE + n0];
#pragma unroll
        for (int i = 0; i < 3; ++i)
#pragma unroll
            for (int j = 0; j < 3; ++j)
                acc[i * 3 + j] = __builtin_amdgcn_mfma_f32_16x16x32_bf16(F[i], F[3 + j], acc[i * 3 + j], 0, 0, 0);
#pragma unroll
        for (int i = 0; i < 3; ++i) {
            acc[9 + i]  = __builtin_amdgcn_mfma_f32_16x16x32_bf16(F[i], F[i], acc[9 + i], 0, 0, 0);
            acc[12 + i] = __builtin_amdgcn_mfma_f32_16x16x32_bf16(F[3 + i], F[3 + i], acc[12 + i], 0, 0, 0);
        }
    }

    // pairwise cross-wave reduce: waves 1,3 -> LDS; waves 0,2 add and store
    __syncthreads();
    if (wave & 1) {
        float* dst = red + (wave >> 1) * (15 * 256);
#pragma unroll
        for (int tt = 0; tt < 15; ++tt)
            *(f32x4*)&dst[tt * 256 + lane * 4] = acc[tt];
    }
    __syncthreads();
    if (!(wave & 1)) {
        const float* src = red + (wave >> 1) * (15 * 256);
        const int sp = slice * 2 + (wave >> 1);     // 0..127
#pragma unroll
        for (int tt = 0; tt < 15; ++tt) {
            f32x4 v = *(const f32x4*)&src[tt * 256 + lane * 4];
#pragma unroll
            for (int r = 0; r < 4; ++r) {
                int e = (quad * 4 + r) * 16 + l15;  // row*16+col of the 16x16 tile
                P[(((size_t)bh * 15 + tt) * 128 + sp) * 256 + e] = acc[tt][r] + v[r];
            }
        }
    }
}

// K3r: sum the 128 per-slice partials; emit S (9 off-diag tiles), NQ/NK (diag tiles)
__global__ __launch_bounds__(256) void k3r_reduce(const float* __restrict__ P,
        float* __restrict__ S, float* __restrict__ NQ, float* __restrict__ NK)
{
    int idx = blockIdx.x * 256 + threadIdx.x;   // 8*15*256 = 30,720 exactly (120 blocks)
    int bh = idx / 3840;
    int rem = idx - bh * 3840;
    int tt = rem >> 8;
    int e = rem & 255;
    const float* p = P + (((size_t)bh * 15 + tt) * 128) * 256 + e;
    float s = 0.f;
#pragma unroll 8
    for (int sp = 0; sp < 128; ++sp) s += p[(size_t)sp * 256];
    int r = e >> 4, c = e & 15;
    if (tt < 9) {
        int i = tt / 3, j = tt - i * 3;
        S[bh * 2304 + (i * 16 + r) * 48 + j * 16 + c] = s;
    } else if (tt < 12) {
        if (r == c) NQ[bh * 48 + (tt - 9) * 16 + r] = s;
    } else {
        if (r == c) NK[bh * 48 + (tt - 12) * 16 + r] = s;
    }
}

// K4a: attn = softmax_row( S * temp / (|q||k|) ), one 64-thread block per (bh,cq) row
__global__ void k4a_softmax(const float* __restrict__ S, const float* __restrict__ NQ,
                            const float* __restrict__ NK, const float* __restrict__ temp,
                            float* __restrict__ ATT)
{
    int bh = blockIdx.y, cq = blockIdx.x;
    int h = bh & 3;
    int t = threadIdx.x;
    float nq = fmaxf(sqrtf(NQ[bh * 48 + cq]), 1e-12f);
    float tv = temp[h];
    float logit = -1e30f;
    if (t < 48) {
        float nk = fmaxf(sqrtf(NK[bh * 48 + t]), 1e-12f);
        logit = S[bh * 2304 + cq * 48 + t] * tv / (nq * nk);
    }
    float m = logit;
    for (int o = 32; o > 0; o >>= 1) m = fmaxf(m, __shfl_xor(m, o));
    float e = (t < 48) ? __expf(logit - m) : 0.f;
    float ssum = e;
    for (int o = 32; o > 0; o >>= 1) ssum += __shfl_xor(ssum, o);
    if (t < 48) ATT[bh * 2304 + cq * 48 + t] = e / ssum;
}

// K4b: fuse attention-apply + output projection into one per-batch 192x192 matrix,
// stored TRANSPOSED so the final GEMM's B-operand reads contiguous K.
__global__ void k4b_buildM(const float* __restrict__ ATT, const float* __restrict__ wout,
                           ushort_t* __restrict__ MT)
{
    int idx = blockIdx.x * 256 + threadIdx.x;      // 2*192*192 = 73728 exactly
    int b = idx / 36864; int rem = idx - b * 36864;
    int j = rem / 192;   int d = rem - j * 192;
    int h = d / 48, dd = d - h * 48;
    const float* ap = ATT + (size_t)(b * 4 + h) * 2304 + dd;   // stride 48 over cq
    const float* wp = wout + (size_t)(h * 48) * 192 + j;       // stride 192 over cq
    float s = 0.f;
#pragma unroll 8
    for (int cq = 0; cq < 48; cq++) s += ap[cq * 48] * wp[cq * 192];
    MT[idx] = f2b(s);
}

extern "C" void kernel_launch(void* const* d_in, const int* in_sizes, int n_in,
                              void* d_out, int out_size, void* d_ws, size_t ws_size,
                              hipStream_t stream) {
    const float* x     = (const float*)d_in[0];
    const float* w_qkv = (const float*)d_in[1];
    const float* b_qkv = (const float*)d_in[2];
    const float* w_dw  = (const float*)d_in[3];
    const float* b_dw  = (const float*)d_in[4];
    const float* temp  = (const float*)d_in[5];
    const float* w_out = (const float*)d_in[6];
    const float* b_out = (const float*)d_in[7];
    float* out = (float*)d_out;

    char* ws = (char*)d_ws;
    ushort_t* qkv0 = (ushort_t*)(ws + OFF_QKV0);
    ushort_t* qkv1 = (ushort_t*)(ws + OFF_QKV1);
    float*    Pb   = (float*)(ws + OFF_P);
    ushort_t* btq  = (ushort_t*)(ws + OFF_BT);
    float*    Sb   = (float*)(ws + OFF_S);
    float*    NQ   = (float*)(ws + OFF_NQ);
    float*    NK   = (float*)(ws + OFF_NK);
    float*    ATT  = (float*)(ws + OFF_ATTN);
    ushort_t* MT   = (ushort_t*)(ws + OFF_MT);

    k0_transpose<<<432, 256, 0, stream>>>(w_qkv, btq);
    // qkv0 = x @ w_qkv + b_qkv  (fp32 A converted in staging; XCD-swizzled 1-D grid:
    // 2048 m-tiles * 9 n-tiles = 18432 blocks)
    gemm_k192<float, ushort_t><<<18432, 256, 0, stream>>>(x, 192, 0, btq, 0, 9, b_qkv, qkv0, 576);
    // qkv1 = depthwise3x3(qkv0) + b_dw   (2*16*256*144 threads / 256 = 4608 blocks)
    k2_dwconv<<<4608, 256, 0, stream>>>(qkv0, w_dw, b_dw, qkv1);
    // MFMA Gram partials (P aliases dead qkv0), then reduce -> S, NQ, NK
    k3_gram_mfma<<<dim3(64, 8), 256, 0, stream>>>(qkv1, Pb);
    k3r_reduce<<<120, 256, 0, stream>>>(Pb, Sb, NQ, NK);
    // softmax(normalized, temperature-scaled)
    k4a_softmax<<<dim3(48, 8), 64, 0, stream>>>(Sb, NQ, NK, temp, ATT);
    // fused (blockdiag attn)^T @ Wout, transposed for the GEMM
    k4b_buildM<<<288, 256, 0, stream>>>(ATT, w_out, MT);
    // out = v @ M_b + b_out   (2048 m-tiles * 3 n-tiles = 6144 blocks)
    gemm_k192<ushort_t, float><<<6144, 256, 0, stream>>>(qkv1, 576, 384, MT, 36864, 3, b_out, out, 192);
}

// Round 8
// 437.163 us; speedup vs baseline: 1.2406x; 1.2406x over previous
//
#include <hip/hip_runtime.h>

typedef unsigned short ushort_t;
typedef __attribute__((ext_vector_type(8))) short short8;
typedef __attribute__((ext_vector_type(4))) float f32x4;

#define B_ 2
#define HW_ 65536          // 256*256 per batch
#define MTOT_ 131072       // B*H*W rows
#define C_ 192
#define C3_ 576
#define HEADS_ 4
#define CH_ 48

// ---- workspace layout (bytes), total ~302.5 MB ----
#define OFF_QKV0  ((size_t)0)                       // bf16 131072*576*2 = 150,994,944
#define OFF_QKV1  ((size_t)150994944)               // bf16, same size
#define OFF_P     OFF_QKV0                          // gram partials (15.7 MB) alias qkv0: dead after dwconv
#define OFF_BT    ((size_t)301989888)               // w_qkv^T bf16 576*192*2 = 221,184
#define OFF_S     ((size_t)302211072)               // fp32 8*48*48 = 73,728 B
#define OFF_NQ    ((size_t)302284800)               // fp32 8*48 = 1,536 B
#define OFF_NK    ((size_t)302286336)               // fp32 8*48 = 1,536 B
#define OFF_ATTN  ((size_t)302287872)               // fp32 8*48*48 = 73,728 B
#define OFF_MT    ((size_t)302361600)               // bf16 2*192*192 = 147,456 B

__device__ __forceinline__ float b2f(ushort_t u) {
    unsigned v = ((unsigned)u) << 16;
    return __builtin_bit_cast(float, v);
}
__device__ __forceinline__ ushort_t f2b(float f) {
    unsigned u = __builtin_bit_cast(unsigned, f);
    u = (u + 0x7fffu + ((u >> 16) & 1u)) >> 16;   // RNE
    return (ushort_t)u;
}
__device__ __forceinline__ void storev(float* p, float v) { *p = v; }
__device__ __forceinline__ void storev(ushort_t* p, float v) { *p = f2b(v); }

// load 16 contiguous A-elements as bf16 pair-of-uint4 (identity for bf16 input,
// RNE convert for fp32 input — bit-identical to the old k_cvt_x pass)
__device__ __forceinline__ void load16(const ushort_t* p, uint4& lo, uint4& hi) {
    lo = *(const uint4*)p;
    hi = *(const uint4*)(p + 8);
}
__device__ __forceinline__ void load16(const float* p, uint4& lo, uint4& hi) {
    float4 a = *(const float4*)p;
    float4 b = *(const float4*)(p + 4);
    float4 c = *(const float4*)(p + 8);
    float4 d = *(const float4*)(p + 12);
    ushort_t o[16];
    o[0]=f2b(a.x); o[1]=f2b(a.y); o[2]=f2b(a.z); o[3]=f2b(a.w);
    o[4]=f2b(b.x); o[5]=f2b(b.y); o[6]=f2b(b.z); o[7]=f2b(b.w);
    o[8]=f2b(c.x); o[9]=f2b(c.y); o[10]=f2b(c.z); o[11]=f2b(c.w);
    o[12]=f2b(d.x); o[13]=f2b(d.y); o[14]=f2b(d.z); o[15]=f2b(d.w);
    lo = *(uint4*)o; hi = *(uint4*)(o + 8);
}

// K0: transpose+convert w_qkv fp32 [192,576] -> bf16 [576,192]
__global__ void k0_transpose(const float* __restrict__ w, ushort_t* __restrict__ bt) {
    int idx = blockIdx.x * 256 + threadIdx.x;        // 576*192 = 110592 exactly
    int n = idx / 192, k = idx - n * 192;
    bt[idx] = f2b(w[k * 576 + n]);
}

// MFMA GEMM: C[M,N] = A[M,192] * BT[N,192]^T(bf16) + bias(fp32).  A fp32 (converted
// during staging) or bf16.  Round-6 K-loop structure (BK=64, 2 barriers/iter,
// 85%-occupancy regime) — round-7's single-shot variant regressed (31% occ).
// ROUND-8 CHANGES target vmem-INSTRUCTION rate (round-6: 160M vmem ops ≈ the
// whole 145us at ~1-2 ops/cyc/CU while HBM sat at 17%, MfmaUtil 8%):
//  (a) each block computes a 64x192 C supertile (3 n-tiles): A staged once per
//      3 n-tiles instead of 3x (A-ops /3).  LDS = As + 3xBs = 36.9KB -> 4 blk/CU.
//  (b) LDS-transposed epilogue: acc -> LDS (wave-private region, no barrier
//      needed after the K-loop's trailing sync) -> re-read row-wise -> uint4
//      global stores.  C-store ops: 16 scalar 2B -> 2x16B per n-tile.
// XCD swizzle kept (round-6: FETCH 395->50MB).  stn = N/192 supertiles.
// Requires gridDim.x % 8 == 0 and (gridDim.x/8) % stn == 0 (6144/2048 ok).
template <typename AT, typename OutT>
__global__ __launch_bounds__(256) void gemm_k192(
    const AT* __restrict__ A, int lda, int acol0,
    const ushort_t* __restrict__ BT, int bstride, int stn,
    const float* __restrict__ bias,
    OutT* __restrict__ Cout, int ldc)
{
    const int per = gridDim.x >> 3;
    const int bid = blockIdx.x;
    const int lb  = (bid & 7) * per + (bid >> 3);
    const int mt  = lb / stn;
    const int m0  = mt * 64;
    const int ns  = (lb - mt * stn) * 192;           // supertile column base
    const ushort_t* bt = BT + (bstride ? (size_t)(m0 >> 16) * (size_t)bstride : 0);

    __shared__ ushort_t SM[4 * 64 * 72];   // As | Bs0 | Bs1 | Bs2  (36,864 B)
    ushort_t* As = SM;

    const int t = threadIdx.x;
    const int wave = t >> 6, lane = t & 63;
    const int quad = lane >> 4, l15 = lane & 15;
    const int wm = (wave >> 1) * 32, wn = (wave & 1) * 32;
    const int srow = t >> 2, scol = (t & 3) * 16;

    f32x4 acc[3][2][2] = {};

    for (int kk = 0; kk < 192; kk += 64) {
        uint4 va0, va1;
        load16(A + (size_t)(m0 + srow) * lda + acol0 + kk + scol, va0, va1);
        uint4 vb[3][2];
#pragma unroll
        for (int nt = 0; nt < 3; ++nt) {
            const ushort_t* gb = bt + (size_t)(ns + nt * 64 + srow) * 192 + kk + scol;
            vb[nt][0] = *(const uint4*)gb;
            vb[nt][1] = *(const uint4*)(gb + 8);
        }
        *(uint4*)&As[srow * 72 + scol] = va0;
        *(uint4*)&As[srow * 72 + scol + 8] = va1;
#pragma unroll
        for (int nt = 0; nt < 3; ++nt) {
            ushort_t* bs = SM + (nt + 1) * 4608;
            *(uint4*)&bs[srow * 72 + scol] = vb[nt][0];
            *(uint4*)&bs[srow * 72 + scol + 8] = vb[nt][1];
        }
        __syncthreads();
#pragma unroll
        for (int ks = 0; ks < 2; ks++) {
            short8 a0 = *(const short8*)&As[(wm + l15) * 72 + ks * 32 + quad * 8];
            short8 a1 = *(const short8*)&As[(wm + 16 + l15) * 72 + ks * 32 + quad * 8];
#pragma unroll
            for (int nt = 0; nt < 3; ++nt) {
                const ushort_t* bs = SM + (nt + 1) * 4608;
                short8 b0 = *(const short8*)&bs[(wn + l15) * 72 + ks * 32 + quad * 8];
                short8 b1 = *(const short8*)&bs[(wn + 16 + l15) * 72 + ks * 32 + quad * 8];
                acc[nt][0][0] = __builtin_amdgcn_mfma_f32_16x16x32_bf16(a0, b0, acc[nt][0][0], 0, 0, 0);
                acc[nt][0][1] = __builtin_amdgcn_mfma_f32_16x16x32_bf16(a0, b1, acc[nt][0][1], 0, 0, 0);
                acc[nt][1][0] = __builtin_amdgcn_mfma_f32_16x16x32_bf16(a1, b0, acc[nt][1][0], 0, 0, 0);
                acc[nt][1][1] = __builtin_amdgcn_mfma_f32_16x16x32_bf16(a1, b1, acc[nt][1][1], 0, 0, 0);
            }
        }
        __syncthreads();
    }

    // ---- LDS-transposed epilogue (SM dead after the loop's trailing sync).
    // Wave-private region: 32 rows x stride 40 elems (80B rows for OutT=ushort
    // keep 16B alignment at 160B for float; both conflict-light).  No barriers:
    // each wave writes and reads only its own region.
    OutT* ew = (OutT*)SM + (size_t)wave * 32 * 40;
    const int erow = lane >> 1, ecol = (lane & 1) * 16;
    constexpr int EPC = 16 / (int)sizeof(OutT);   // elems per 16B chunk
    constexpr int NCH = 16 / EPC;                 // chunks per lane (2 or 4)
#pragma unroll
    for (int nt = 0; nt < 3; ++nt) {
        const int n0g = ns + nt * 64;
#pragma unroll
        for (int sm = 0; sm < 2; sm++)
#pragma unroll
            for (int sn = 0; sn < 2; sn++) {
                float bv = bias ? bias[n0g + wn + sn * 16 + l15] : 0.f;
#pragma unroll
                for (int r = 0; r < 4; r++)
                    storev(&ew[(sm * 16 + quad * 4 + r) * 40 + sn * 16 + l15],
                           acc[nt][sm][sn][r] + bv);
            }
        const OutT* er = ew + erow * 40 + ecol;
        OutT* gp = Cout + (size_t)(m0 + wm + erow) * ldc + n0g + wn + ecol;
#pragma unroll
        for (int h = 0; h < NCH; ++h)
            *(uint4*)(gp + h * EPC) = *(const uint4*)(er + h * EPC);
    }
}

// K2: 3x3 depthwise conv, SAME zero-pad, fp32 weights/bias, bf16 act in/out.
// Register-sliding, 4 channels/thread: each thread owns (b, x, c4) and a strip
// of 16 output rows.  Threads: 2*16*256*144 = 1,179,648 -> grid 4608 x 256.
#define R_STRIP 16

__global__ __launch_bounds__(256) void k2_dwconv(const ushort_t* __restrict__ qkv0,
        const float* __restrict__ wdw, const float* __restrict__ bdw,
        ushort_t* __restrict__ qkv1)
{
    const int tid = blockIdx.x * 256 + threadIdx.x;   // < 1,179,648
    const int c4 = tid % 144;
    const int t1 = tid / 144;                 // = (b*16 + s)*256 + x, < 8192
    const int x  = t1 & 255;
    const int t2 = t1 >> 8;
    const int s  = t2 & 15;
    const int b  = t2 >> 4;
    const int y0 = s * R_STRIP;
    const int cbase = c4 * 4;

    const bool xm = (x > 0), xp = (x < 255);
    const ushort_t* colbase = qkv0 + ((size_t)(b * HW_ + x) * C3_ + cbase);
    ushort_t*       ocol    = qkv1 + ((size_t)(b * HW_ + x) * C3_ + cbase);
    const size_t rstride = (size_t)256 * C3_;         // elems per image row

    // preload weights [ky][kx][4] and bias (coalesced float4 reads, L2-hot)
    float w[3][3][4], bw[4];
#pragma unroll
    for (int ky = 0; ky < 3; ++ky)
#pragma unroll
        for (int kx = 0; kx < 3; ++kx) {
            float4 wv = *(const float4*)(wdw + ((ky * 3 + kx) * C3_ + cbase));
            w[ky][kx][0] = wv.x; w[ky][kx][1] = wv.y; w[ky][kx][2] = wv.z; w[ky][kx][3] = wv.w;
        }
    {
        float4 bv = *(const float4*)(bdw + cbase);
        bw[0] = bv.x; bw[1] = bv.y; bw[2] = bv.z; bw[3] = bv.w;
    }

    const uint2 z2 = make_uint2(0, 0);
    auto loadrow = [&](int r, uint2& d0, uint2& d1, uint2& d2) {
        if ((unsigned)r <= 255u) {
            const ushort_t* p = colbase + (size_t)r * rstride;
            d1 = *(const uint2*)p;
            d0 = xm ? *(const uint2*)(p - C3_) : z2;
            d2 = xp ? *(const uint2*)(p + C3_) : z2;
        } else { d0 = z2; d1 = z2; d2 = z2; }
    };

    // acc role: output row o uses A[(o - y0 + 1) % 3]; at step RR (input row
    // r = y0-1+RR): prev-out(r-1) -> (RR+2)%3, cur-out(r) -> RR%3,
    // next-out(r+1) -> (RR+1)%3 — all compile-time after unroll.
    float A[3][4] = {};
    uint2 c0, c1, c2;
    loadrow(y0 - 1, c0, c1, c2);

#pragma unroll
    for (int RR = 0; RR < R_STRIP + 2; ++RR) {
        const int r = y0 - 1 + RR;
        uint2 n0 = z2, n1 = z2, n2 = z2;
        if (RR < R_STRIP + 1) loadrow(r + 1, n0, n1, n2);   // 1-step prefetch

        float rf[3][4];
        {
            const ushort_t* dd = (const ushort_t*)&c0;
#pragma unroll
            for (int j = 0; j < 4; ++j) rf[0][j] = b2f(dd[j]);
            dd = (const ushort_t*)&c1;
#pragma unroll
            for (int j = 0; j < 4; ++j) rf[1][j] = b2f(dd[j]);
            dd = (const ushort_t*)&c2;
#pragma unroll
            for (int j = 0; j < 4; ++j) rf[2][j] = b2f(dd[j]);
        }

        if (RR >= 1 && RR <= R_STRIP) {           // row r -> out r (ky=0 center)
#pragma unroll
            for (int kx = 0; kx < 3; ++kx)
#pragma unroll
                for (int j = 0; j < 4; ++j)
                    A[RR % 3][j] = fmaf(rf[kx][j], w[1][kx][j], A[RR % 3][j]);
        }
        if (RR <= R_STRIP - 1) {                  // row r -> out r+1 (ky=-1)
#pragma unroll
            for (int kx = 0; kx < 3; ++kx)
#pragma unroll
                for (int j = 0; j < 4; ++j)
                    A[(RR + 1) % 3][j] = fmaf(rf[kx][j], w[0][kx][j], A[(RR + 1) % 3][j]);
        }
        if (RR >= 2) {                            // row r -> out r-1 (ky=+1), emit r-1
#pragma unroll
            for (int kx = 0; kx < 3; ++kx)
#pragma unroll
                for (int j = 0; j < 4; ++j)
                    A[(RR + 2) % 3][j] = fmaf(rf[kx][j], w[2][kx][j], A[(RR + 2) % 3][j]);
            ushort_t ov[4];
#pragma unroll
            for (int j = 0; j < 4; ++j) {
                ov[j] = f2b(A[(RR + 2) % 3][j] + bw[j]);
                A[(RR + 2) % 3][j] = 0.f;
            }
            *(uint2*)(ocol + (size_t)(r - 1) * rstride) = *(uint2*)ov;
        }
        c0 = n0; c1 = n1; c2 = n2;
    }
}

// K3 (MFMA): per (b,head) 96x96 Gram of Z=[Q|K] over a 1024-row slice.
#define GR_LDSSTRIDE 136

__global__ __launch_bounds__(256) void k3_gram_mfma(const ushort_t* __restrict__ qkv1,
        float* __restrict__ P)
{
    const int bh = blockIdx.y;              // 0..7
    const int b = bh >> 2, h = bh & 3;
    const int slice = blockIdx.x;           // 0..63
    const int t = threadIdx.x;
    const int wave = t >> 6, lane = t & 63;
    const int quad = lane >> 4, l15 = lane & 15;

    __shared__ float red[7680];             // 30,720 B; low 26,112 B doubles as bf16 stage
    ushort_t* Z = (ushort_t*)red;

    f32x4 acc[15] = {};
    const ushort_t* basep = qkv1 + (size_t)(b * HW_) * C3_;
    const int row = t & 127;
    const int seghalf = t >> 7;             // 0: even segs, 1: odd segs

    for (int tile = 0; tile < 8; ++tile) {
        const int nbase = slice * 1024 + tile * 128;
        uint4 u[6];
#pragma unroll
        for (int k = 0; k < 6; ++k) {       // issue loads before barrier: overlap prev compute
            int seg = k * 2 + seghalf;      // 0..11; segs 0-5 = Q chans, 6-11 = K chans
            int cg = (seg < 6) ? (h * CH_ + seg * 8) : (C_ + h * CH_ + (seg - 6) * 8);
            u[k] = *(const uint4*)(basep + (size_t)(nbase + row) * C3_ + cg);
        }
        __syncthreads();                    // previous tile's compute done
#pragma unroll
        for (int k = 0; k < 6; ++k) {
            int seg = k * 2 + seghalf;
            int zc = seg * 8;               // z-channel base (Q:0-47, K:48-95)
            const ushort_t* dd = (const ushort_t*)&u[k];
#pragma unroll
            for (int j = 0; j < 8; ++j)
                Z[(zc + j) * GR_LDSSTRIDE + row] = dd[j];
        }
        __syncthreads();
        const int n0 = wave * 32 + quad * 8;
        short8 F[6];
#pragma unroll
        for (int c = 0; c < 6; ++c)
            F[c] = *(const short8*)&Z[(c * 16 + l15) * GR_LDSSTRIDE + n0];
#pragma unroll
        for (int i = 0; i < 3; ++i)
#pragma unroll
            for (int j = 0; j < 3; ++j)
                acc[i * 3 + j] = __builtin_amdgcn_mfma_f32_16x16x32_bf16(F[i], F[3 + j], acc[i * 3 + j], 0, 0, 0);
#pragma unroll
        for (int i = 0; i < 3; ++i) {
            acc[9 + i]  = __builtin_amdgcn_mfma_f32_16x16x32_bf16(F[i], F[i], acc[9 + i], 0, 0, 0);
            acc[12 + i] = __builtin_amdgcn_mfma_f32_16x16x32_bf16(F[3 + i], F[3 + i], acc[12 + i], 0, 0, 0);
        }
    }

    // pairwise cross-wave reduce: waves 1,3 -> LDS; waves 0,2 add and store
    __syncthreads();
    if (wave & 1) {
        float* dst = red + (wave >> 1) * (15 * 256);
#pragma unroll
        for (int tt = 0; tt < 15; ++tt)
            *(f32x4*)&dst[tt * 256 + lane * 4] = acc[tt];
    }
    __syncthreads();
    if (!(wave & 1)) {
        const float* src = red + (wave >> 1) * (15 * 256);
        const int sp = slice * 2 + (wave >> 1);     // 0..127
#pragma unroll
        for (int tt = 0; tt < 15; ++tt) {
            f32x4 v = *(const f32x4*)&src[tt * 256 + lane * 4];
#pragma unroll
            for (int r = 0; r < 4; ++r) {
                int e = (quad * 4 + r) * 16 + l15;  // row*16+col of the 16x16 tile
                P[(((size_t)bh * 15 + tt) * 128 + sp) * 256 + e] = acc[tt][r] + v[r];
            }
        }
    }
}

// K3r: sum the 128 per-slice partials; emit S (9 off-diag tiles), NQ/NK (diag tiles)
__global__ __launch_bounds__(256) void k3r_reduce(const float* __restrict__ P,
        float* __restrict__ S, float* __restrict__ NQ, float* __restrict__ NK)
{
    int idx = blockIdx.x * 256 + threadIdx.x;   // 8*15*256 = 30,720 exactly (120 blocks)
    int bh = idx / 3840;
    int rem = idx - bh * 3840;
    int tt = rem >> 8;
    int e = rem & 255;
    const float* p = P + (((size_t)bh * 15 + tt) * 128) * 256 + e;
    float s = 0.f;
#pragma unroll 8
    for (int sp = 0; sp < 128; ++sp) s += p[(size_t)sp * 256];
    int r = e >> 4, c = e & 15;
    if (tt < 9) {
        int i = tt / 3, j = tt - i * 3;
        S[bh * 2304 + (i * 16 + r) * 48 + j * 16 + c] = s;
    } else if (tt < 12) {
        if (r == c) NQ[bh * 48 + (tt - 9) * 16 + r] = s;
    } else {
        if (r == c) NK[bh * 48 + (tt - 12) * 16 + r] = s;
    }
}

// K4a: attn = softmax_row( S * temp / (|q||k|) ), one 64-thread block per (bh,cq) row
__global__ void k4a_softmax(const float* __restrict__ S, const float* __restrict__ NQ,
                            const float* __restrict__ NK, const float* __restrict__ temp,
                            float* __restrict__ ATT)
{
    int bh = blockIdx.y, cq = blockIdx.x;
    int h = bh & 3;
    int t = threadIdx.x;
    float nq = fmaxf(sqrtf(NQ[bh * 48 + cq]), 1e-12f);
    float tv = temp[h];
    float logit = -1e30f;
    if (t < 48) {
        float nk = fmaxf(sqrtf(NK[bh * 48 + t]), 1e-12f);
        logit = S[bh * 2304 + cq * 48 + t] * tv / (nq * nk);
    }
    float m = logit;
    for (int o = 32; o > 0; o >>= 1) m = fmaxf(m, __shfl_xor(m, o));
    float e = (t < 48) ? __expf(logit - m) : 0.f;
    float ssum = e;
    for (int o = 32; o > 0; o >>= 1) ssum += __shfl_xor(ssum, o);
    if (t < 48) ATT[bh * 2304 + cq * 48 + t] = e / ssum;
}

// K4b: fuse attention-apply + output projection into one per-batch 192x192 matrix,
// stored TRANSPOSED so the final GEMM's B-operand reads contiguous K.
__global__ void k4b_buildM(const float* __restrict__ ATT, const float* __restrict__ wout,
                           ushort_t* __restrict__ MT)
{
    int idx = blockIdx.x * 256 + threadIdx.x;      // 2*192*192 = 73728 exactly
    int b = idx / 36864; int rem = idx - b * 36864;
    int j = rem / 192;   int d = rem - j * 192;
    int h = d / 48, dd = d - h * 48;
    const float* ap = ATT + (size_t)(b * 4 + h) * 2304 + dd;   // stride 48 over cq
    const float* wp = wout + (size_t)(h * 48) * 192 + j;       // stride 192 over cq
    float s = 0.f;
#pragma unroll 8
    for (int cq = 0; cq < 48; cq++) s += ap[cq * 48] * wp[cq * 192];
    MT[idx] = f2b(s);
}

extern "C" void kernel_launch(void* const* d_in, const int* in_sizes, int n_in,
                              void* d_out, int out_size, void* d_ws, size_t ws_size,
                              hipStream_t stream) {
    const float* x     = (const float*)d_in[0];
    const float* w_qkv = (const float*)d_in[1];
    const float* b_qkv = (const float*)d_in[2];
    const float* w_dw  = (const float*)d_in[3];
    const float* b_dw  = (const float*)d_in[4];
    const float* temp  = (const float*)d_in[5];
    const float* w_out = (const float*)d_in[6];
    const float* b_out = (const float*)d_in[7];
    float* out = (float*)d_out;

    char* ws = (char*)d_ws;
    ushort_t* qkv0 = (ushort_t*)(ws + OFF_QKV0);
    ushort_t* qkv1 = (ushort_t*)(ws + OFF_QKV1);
    float*    Pb   = (float*)(ws + OFF_P);
    ushort_t* btq  = (ushort_t*)(ws + OFF_BT);
    float*    Sb   = (float*)(ws + OFF_S);
    float*    NQ   = (float*)(ws + OFF_NQ);
    float*    NK   = (float*)(ws + OFF_NK);
    float*    ATT  = (float*)(ws + OFF_ATTN);
    ushort_t* MT   = (ushort_t*)(ws + OFF_MT);

    k0_transpose<<<432, 256, 0, stream>>>(w_qkv, btq);
    // qkv0 = x @ w_qkv + b_qkv  (fp32 A converted in staging; XCD-swizzled 1-D grid:
    // 2048 m-tiles * 3 supertiles (192 cols each) = 6144 blocks)
    gemm_k192<float, ushort_t><<<6144, 256, 0, stream>>>(x, 192, 0, btq, 0, 3, b_qkv, qkv0, 576);
    // qkv1 = depthwise3x3(qkv0) + b_dw   (2*16*256*144 threads / 256 = 4608 blocks)
    k2_dwconv<<<4608, 256, 0, stream>>>(qkv0, w_dw, b_dw, qkv1);
    // MFMA Gram partials (P aliases dead qkv0), then reduce -> S, NQ, NK
    k3_gram_mfma<<<dim3(64, 8), 256, 0, stream>>>(qkv1, Pb);
    k3r_reduce<<<120, 256, 0, stream>>>(Pb, Sb, NQ, NK);
    // softmax(normalized, temperature-scaled)
    k4a_softmax<<<dim3(48, 8), 64, 0, stream>>>(Sb, NQ, NK, temp, ATT);
    // fused (blockdiag attn)^T @ Wout, transposed for the GEMM
    k4b_buildM<<<288, 256, 0, stream>>>(ATT, w_out, MT);
    // out = v @ M_b + b_out   (2048 m-tiles * 1 supertile = 2048 blocks)
    gemm_k192<ushort_t, float><<<2048, 256, 0, stream>>>(qkv1, 576, 384, MT, 36864, 1, b_out, out, 192);
}